// Round 3
// baseline (561.515 us; speedup 1.0000x reference)
//
#include <hip/hip_runtime.h>

typedef _Float16 half_t;
typedef __attribute__((ext_vector_type(8))) _Float16 half8;
typedef __attribute__((ext_vector_type(4))) float floatx4;

#define BM 128
#define BN 128
#define BK 32

// ---------------- conversion + rearrange: W[d][s*C+c] -> Wt[c][s*D+d] fp16 ----------------
// also computes tanh(bias) table (threads idx < C)
__global__ void cvt_w_kernel(const float* __restrict__ W, half_t* __restrict__ Wt,
                             const float* __restrict__ bias, float* __restrict__ tb,
                             int D, int C, int total) {
    int idx = blockIdx.x * blockDim.x + threadIdx.x;  // idx = c*1536 + s*512 + d
    if (idx >= total) return;
    if (idx < C) {
        float ex = __expf(2.0f * bias[idx]);
        tb[idx] = 1.0f - 2.0f / (ex + 1.0f);
    }
    int c = idx / 1536;
    int r = idx - c * 1536;           // s*512 + d
    int s = r >> 9;
    int d = r & 511;
    Wt[idx] = (half_t)W[(long)d * 1536 + s * 512 + c];
}

// ---------------- counting sort of edges by dst ----------------
__global__ void hist_kernel(const int* __restrict__ dst, int* __restrict__ deg, int E) {
    int e = blockIdx.x * blockDim.x + threadIdx.x;
    if (e < E) atomicAdd(&deg[dst[e]], 1);
}

// partial sums of deg AND of flag(deg>0), per 1024-element block
__global__ void scan_partial2_kernel(const int* __restrict__ deg,
                                     int* __restrict__ bsum, int* __restrict__ bsum2, int n) {
    __shared__ int wsum[4], wsum2[4];
    int t = threadIdx.x, lane = t & 63, w = t >> 6;
    int base = blockIdx.x * 1024 + t * 4;
    int s = 0, s2 = 0;
#pragma unroll
    for (int j = 0; j < 4; ++j) {
        int i = base + j;
        if (i < n) { int d = deg[i]; s += d; s2 += (d > 0); }
    }
#pragma unroll
    for (int o = 1; o < 64; o <<= 1) { s += __shfl_xor(s, o); s2 += __shfl_xor(s2, o); }
    if (lane == 0) { wsum[w] = s; wsum2[w] = s2; }
    __syncthreads();
    if (t == 0) {
        bsum[blockIdx.x]  = wsum[0]  + wsum[1]  + wsum[2]  + wsum[3];
        bsum2[blockIdx.x] = wsum2[0] + wsum2[1] + wsum2[2] + wsum2[3];
    }
}

// single-wave exclusive scan of up to 128 elements in-place; returns total
__device__ int exscan_wave128(int* arr, int nb, int lane) {
    int a0 = (lane < nb) ? arr[lane] : 0;
    int a1 = (64 + lane < nb) ? arr[64 + lane] : 0;
    int s0 = a0, s1 = a1;
#pragma unroll
    for (int o = 1; o < 64; o <<= 1) {
        int t0 = __shfl_up(s0, o); if (lane >= o) s0 += t0;
        int t1 = __shfl_up(s1, o); if (lane >= o) s1 += t1;
    }
    s1 += __shfl(s0, 63);
    int tot = __shfl(s1, 63);
    if (lane < nb) arr[lane] = s0 - a0;
    if (64 + lane < nb) arr[64 + lane] = s1 - a1;
    return tot;
}

__global__ void scan_bsums2_kernel(int* __restrict__ bsum, int* __restrict__ bsum2,
                                   int nb, int* __restrict__ mc) {
    int lane = threadIdx.x & 63;
    if (nb <= 128) {
        exscan_wave128(bsum, nb, lane);
        int tot = exscan_wave128(bsum2, nb, lane);
        if (lane == 0) *mc = tot;
    } else if (lane == 0) {
        int acc = 0, acc2 = 0;
        for (int i = 0; i < nb; ++i) {
            int v = bsum[i];  bsum[i] = acc;   acc += v;
            int v2 = bsum2[i]; bsum2[i] = acc2; acc2 += v2;
        }
        *mc = acc2;
    }
}

// final scan: edge offsets (off) + compact row rank + nodeid (compact->node)
__global__ void scan_final2_kernel(const int* __restrict__ deg,
                                   const int* __restrict__ bsum, const int* __restrict__ bsum2,
                                   int* __restrict__ off, int* __restrict__ rank,
                                   int* __restrict__ nodeid, int n) {
    __shared__ int wsum[4], wsum2[4];
    int t = threadIdx.x, lane = t & 63, w = t >> 6;
    int base = blockIdx.x * 1024 + t * 4;
    int v[4]; int s = 0, s2 = 0;
#pragma unroll
    for (int j = 0; j < 4; ++j) {
        int i = base + j;
        v[j] = (i < n) ? deg[i] : 0;
        s += v[j]; s2 += (v[j] > 0);
    }
    int sc = s, sc2 = s2;
#pragma unroll
    for (int o = 1; o < 64; o <<= 1) {
        int u  = __shfl_up(sc, o);  if (lane >= o) sc  += u;
        int u2 = __shfl_up(sc2, o); if (lane >= o) sc2 += u2;
    }
    if (lane == 63) { wsum[w] = sc; wsum2[w] = sc2; }
    __syncthreads();
    int woff = 0, woff2 = 0;
    for (int i = 0; i < w; ++i) { woff += wsum[i]; woff2 += wsum2[i]; }
    int ex  = bsum[blockIdx.x]  + woff  + (sc  - s);
    int ex2 = bsum2[blockIdx.x] + woff2 + (sc2 - s2);
#pragma unroll
    for (int j = 0; j < 4; ++j) {
        int i = base + j;
        if (i < n) {
            off[i] = ex;
            if (v[j] > 0) { rank[i] = ex2; nodeid[ex2] = i; ex2++; }
            ex += v[j];
        }
    }
}

// scatter: edges sorted by dst; also pre-gathers src + eta so aggx has a 2-level chain
__global__ void scatter_kernel(const int* __restrict__ dst, const int* __restrict__ src,
                               const float* __restrict__ eta,
                               const int* __restrict__ off, int* __restrict__ cursor,
                               int* __restrict__ srcs, floatx4* __restrict__ etas, int E) {
    int e = blockIdx.x * blockDim.x + threadIdx.x;
    if (e >= E) return;
    int d = dst[e];
    int p = off[d] + atomicAdd(&cursor[d], 1);
    srcs[p] = src[e];
    floatx4 et;
    et[0] = eta[3 * e + 0]; et[1] = eta[3 * e + 1]; et[2] = eta[3 * e + 2]; et[3] = 0.0f;
    etas[p] = et;
}

// ---------------- pre-aggregation: compacted Z[rank[n]][s*D+d]; deg-0 -> out=tanh(bias) ----------------
__global__ __launch_bounds__(256) void aggx_kernel(
    const float* __restrict__ x, const int* __restrict__ srcs,
    const floatx4* __restrict__ etas, const int* __restrict__ off,
    const int* __restrict__ deg, const int* __restrict__ rank,
    const float* __restrict__ tb, float* __restrict__ out,
    half_t* __restrict__ Z, int N, int D, int C)
{
    int node = blockIdx.x * 4 + (threadIdx.x >> 6);
    if (node >= N) return;
    int lane = threadIdx.x & 63;
    int d = deg[node];
    if (d == 0) {
        // no in-edges: out row = tanh(bias) (precomputed); nontemporal (write-once, never re-read)
        float* o = out + (long)node * C;
        for (int c0 = lane * 8; c0 < C; c0 += 64 * 8) {
            floatx4 v0 = *(const floatx4*)(tb + c0);
            floatx4 v1 = *(const floatx4*)(tb + c0 + 4);
            __builtin_nontemporal_store(v0, (floatx4*)(o + c0));
            __builtin_nontemporal_store(v1, (floatx4*)(o + c0 + 4));
        }
        return;
    }

    float a0[8] = {}, a1[8] = {}, a2[8] = {};
    int start = off[node];
    for (int q = 0; q < d; ++q) {
        int s = srcs[start + q];          // wave-uniform broadcast
        floatx4 et = etas[start + q];     // wave-uniform broadcast
        const float* xr = x + (long)s * D + lane * 8;
        floatx4 v0 = *(const floatx4*)xr;
        floatx4 v1 = *(const floatx4*)(xr + 4);
#pragma unroll
        for (int j = 0; j < 4; ++j) {
            a0[j] += et[0] * v0[j]; a0[j + 4] += et[0] * v1[j];
            a1[j] += et[1] * v0[j]; a1[j + 4] += et[1] * v1[j];
            a2[j] += et[2] * v0[j]; a2[j + 4] += et[2] * v1[j];
        }
    }
    half_t* zr = Z + (long)rank[node] * (3 * D) + lane * 8;
    half8 h0, h1, h2;
#pragma unroll
    for (int j = 0; j < 8; ++j) { h0[j] = (half_t)a0[j]; h1[j] = (half_t)a1[j]; h2[j] = (half_t)a2[j]; }
    *(half8*)zr = h0;
    *(half8*)(zr + D) = h1;
    *(half8*)(zr + 2 * D) = h2;
}

// ---------------- GEMM + bias + tanh over compacted rows, epilogue scatter ----------------
// 128^2 tile, TRIPLE-buffered LDS, 2-step prefetch with counted vmcnt(8) + raw s_barrier:
// tile t+2's loads issued at step t -> ~2 steps (>1100 cy) in flight before use, covering
// the ~700-900 cy L3/HBM latency that the 2-buffer version stalled on every step.
__global__ __launch_bounds__(256) void gemm_tanh_kernel(
    const half_t* __restrict__ A,    // compacted Z: [Mc][K], K=1536
    const half_t* __restrict__ Bt,   // Wt: [C][K]
    const float* __restrict__ bias,  // [C]
    const int* __restrict__ mc_ptr,  // &Mc
    const int* __restrict__ nodeid,  // compact row -> node
    float* __restrict__ out,         // [N][C]
    int K, int C)
{
    __shared__ half_t As[3][BM * BK];
    __shared__ half_t Bs[3][BN * BK];

    const int Mc = *mc_ptr;
    const int ncol = C / BN;                         // 4
    const int T = ((Mc + BM - 1) / BM) * ncol;       // live tiles
    const int b = blockIdx.x;
    if (b >= T) return;
    // bijective XCD swizzle (m204): contiguous tile chunk per XCD, cols fastest
    const int qq = T >> 3, rem = T & 7;
    const int xcd = b & 7, ib = b >> 3;
    const int wg = (xcd < rem ? xcd * (qq + 1) : rem * (qq + 1) + (xcd - rem) * qq) + ib;
    const int n0 = (wg % ncol) * BN;
    const int m0 = (wg / ncol) * BM;

    const int t    = threadIdx.x;
    const int lane = t & 63;
    const int wave = t >> 6;
    const int wm   = (wave >> 1) * 64;
    const int wn   = (wave & 1) * 64;

    // staging: thread t stages row r=t>>2 (and r+64), LDS slot t&3 (dest linear: t*16B).
    // source octet swizzled: o_g = (t&3) ^ ((t>>3)&3)  (both-sides-or-neither, rule #21)
    const int r1 = t >> 2;
    const int r2 = r1 + 64;
    const int k8 = (((t & 3) ^ ((t >> 3) & 3))) * 8;
    const long gA1 = (long)(m0 + r1) * K + k8;   // Z padded to BM multiple: in-bounds
    const long gA2 = (long)(m0 + r2) * K + k8;
    const long gB1 = (long)(n0 + r1) * K + k8;
    const long gB2 = (long)(n0 + r2) * K + k8;

    floatx4 acc[4][4] = {};

    const int mrow = wm + (lane & 15);
    const int nrow = wn + (lane & 15);
    const int koff = (((lane >> 4) ^ ((lane >> 1) & 3))) * 8;

#define STAGE(buf, kt)                                                                     \
    do {                                                                                   \
        __builtin_amdgcn_global_load_lds(                                                  \
            (const __attribute__((address_space(1))) void*)(A + gA1 + (kt)),               \
            (__attribute__((address_space(3))) void*)(&As[buf][t * 8]), 16, 0, 0);         \
        __builtin_amdgcn_global_load_lds(                                                  \
            (const __attribute__((address_space(1))) void*)(A + gA2 + (kt)),               \
            (__attribute__((address_space(3))) void*)(&As[buf][(t + 256) * 8]), 16, 0, 0); \
        __builtin_amdgcn_global_load_lds(                                                  \
            (const __attribute__((address_space(1))) void*)(Bt + gB1 + (kt)),              \
            (__attribute__((address_space(3))) void*)(&Bs[buf][t * 8]), 16, 0, 0);         \
        __builtin_amdgcn_global_load_lds(                                                  \
            (const __attribute__((address_space(1))) void*)(Bt + gB2 + (kt)),              \
            (__attribute__((address_space(3))) void*)(&Bs[buf][(t + 256) * 8]), 16, 0, 0); \
    } while (0)

#define COMPUTE(buf)                                                                       \
    do {                                                                                   \
        half8 af[4], bf[4];                                                                \
        _Pragma("unroll") for (int i = 0; i < 4; ++i)                                      \
            af[i] = *(const half8*)&As[buf][(mrow + i * 16) * BK + koff];                   \
        _Pragma("unroll") for (int i = 0; i < 4; ++i)                                      \
            bf[i] = *(const half8*)&Bs[buf][(nrow + i * 16) * BK + koff];                   \
        _Pragma("unroll") for (int i = 0; i < 4; ++i)                                      \
            _Pragma("unroll") for (int j = 0; j < 4; ++j)                                  \
                acc[i][j] = __builtin_amdgcn_mfma_f32_16x16x32_f16(af[i], bf[j],           \
                                                                   acc[i][j], 0, 0, 0);   \
    } while (0)

    const int nsteps = K / BK;   // 48
    int b0 = 0, b1 = 1, b2 = 2;
    STAGE(0, 0);
    STAGE(1, BK);
    for (int ks = 0; ks < nsteps - 2; ++ks) {
        STAGE(b2, (ks + 2) * BK);                       // 12 loads now in flight
        asm volatile("s_waitcnt vmcnt(8)" ::: "memory"); // retire oldest 4 = tile ks's loads
        __builtin_amdgcn_sched_barrier(0);
        __builtin_amdgcn_s_barrier();                   // all waves: buf b0 complete
        __builtin_amdgcn_sched_barrier(0);
        COMPUTE(b0);
        __builtin_amdgcn_sched_barrier(0);
        __builtin_amdgcn_s_barrier();                   // b0 free for overwrite (stage at ks+1 hits it? no: ks+1 stages old b1's slot -- see rotation; this barrier protects buf read this step, staged next step)
        __builtin_amdgcn_sched_barrier(0);
        int tmp = b0; b0 = b1; b1 = b2; b2 = tmp;
    }
    // tail: tiles nsteps-2 (in b0) and nsteps-1 (in b1); 8 loads outstanding
    asm volatile("s_waitcnt vmcnt(4)" ::: "memory");
    __builtin_amdgcn_sched_barrier(0);
    __builtin_amdgcn_s_barrier();
    __builtin_amdgcn_sched_barrier(0);
    COMPUTE(b0);
    asm volatile("s_waitcnt vmcnt(0)" ::: "memory");
    __builtin_amdgcn_sched_barrier(0);
    __builtin_amdgcn_s_barrier();
    __builtin_amdgcn_sched_barrier(0);
    COMPUTE(b1);

#undef STAGE
#undef COMPUTE

    // epilogue: D[m][n]: col = lane&15, row = (lane>>4)*4 + reg; scatter via nodeid; bias + tanh
    // out is write-once, never re-read -> nontemporal stores (keep x/Z in L3)
    const int col0 = lane & 15;
    const int rbase = (lane >> 4) * 4;
    float bj[4];
#pragma unroll
    for (int j = 0; j < 4; ++j)
        bj[j] = bias[n0 + wn + col0 + j * 16];
#pragma unroll
    for (int i = 0; i < 4; ++i) {
#pragma unroll
        for (int rr = 0; rr < 4; ++rr) {
            int crow = m0 + wm + i * 16 + rbase + rr;
            if (crow >= Mc) continue;
            long base = (long)nodeid[crow] * C + n0 + wn + col0;
#pragma unroll
            for (int j = 0; j < 4; ++j) {
                float xv = acc[i][j][rr] + bj[j];
                float ex = __expf(2.0f * xv);
                __builtin_nontemporal_store(1.0f - 2.0f / (ex + 1.0f), &out[base + j * 16]);
            }
        }
    }
}

extern "C" void kernel_launch(void* const* d_in, const int* in_sizes, int n_in,
                              void* d_out, int out_size, void* d_ws, size_t ws_size,
                              hipStream_t stream) {
    const float* x    = (const float*)d_in[0];
    const float* W    = (const float*)d_in[1];
    const float* bias = (const float*)d_in[2];
    const float* eta  = (const float*)d_in[3];
    const int*   src  = (const int*)d_in[4];
    const int*   dst  = (const int*)d_in[5];
    float* out = (float*)d_out;

    const int  C   = in_sizes[2];          // 512
    const int  C3  = 3 * C;                // 1536
    const int  D   = in_sizes[1] / C3;     // 512
    const long xcount = in_sizes[0];       // N*D
    const int  N   = (int)(xcount / D);    // 100000
    const int  E   = in_sizes[4];          // 100000
    const int  K   = 3 * D;                // 1536 (GEMM inner dim)
    const int  Npad = ((N + BM - 1) / BM) * BM;
    const int  nb  = (N + 1023) / 1024;
    const size_t nbPad = (size_t)((nb + 3) & ~3);

    auto alignup = [](size_t v) { return (v + 15) & ~(size_t)15; };

    // workspace: Z | Wt | deg | cursor | off | rank | nodeid | srcs | etas | bsum | bsum2 | mc | tb
    char* ws = (char*)d_ws;
    size_t o = 0;
    half_t* Z    = (half_t*)(ws + o); o += (size_t)Npad * K * sizeof(half_t);
    half_t* Wt_h = (half_t*)(ws + o); o += (size_t)C * K * sizeof(half_t);
    int* deg     = (int*)(ws + o);    o += (size_t)N * sizeof(int);
    int* cursor  = (int*)(ws + o);    o += (size_t)N * sizeof(int);
    int* off     = (int*)(ws + o);    o += (size_t)N * sizeof(int);
    int* rank    = (int*)(ws + o);    o += (size_t)N * sizeof(int);
    int* nodeid  = (int*)(ws + o);    o += (size_t)N * sizeof(int);
    int* srcs    = (int*)(ws + o);    o += (size_t)E * sizeof(int);
    o = alignup(o);
    floatx4* etas = (floatx4*)(ws + o); o += (size_t)E * sizeof(floatx4);
    int* bsum    = (int*)(ws + o);    o += nbPad * sizeof(int);
    int* bsum2   = (int*)(ws + o);    o += nbPad * sizeof(int);
    int* mc      = (int*)(ws + o);    o += 4 * sizeof(int);
    float* tb    = (float*)(ws + o);  o += (size_t)C * sizeof(float);

    // 0. zero deg + cursor (adjacent)
    hipMemsetAsync(deg, 0, 2 * (size_t)N * sizeof(int), stream);
    // 1. W -> fp16 [C][3*D] + tanh(bias) table
    cvt_w_kernel<<<(C * K + 255) / 256, 256, 0, stream>>>(W, Wt_h, bias, tb, D, C, C * K);
    // 2. counting sort of edges by dst + compaction scan (rank/nodeid/Mc)
    hist_kernel<<<(E + 255) / 256, 256, 0, stream>>>(dst, deg, E);
    scan_partial2_kernel<<<nb, 256, 0, stream>>>(deg, bsum, bsum2, N);
    scan_bsums2_kernel<<<1, 64, 0, stream>>>(bsum, bsum2, nb, mc);
    scan_final2_kernel<<<nb, 256, 0, stream>>>(deg, bsum, bsum2, off, rank, nodeid, N);
    scatter_kernel<<<(E + 255) / 256, 256, 0, stream>>>(dst, src, eta, off, cursor, srcs, etas, E);
    // 3. pre-aggregation -> compacted Z (fp16); deg-0 rows -> tanh(bias) row
    aggx_kernel<<<(N + 3) / 4, 256, 0, stream>>>(x, srcs, etas, off, deg, rank, tb, out, Z, N, D, C);
    // 4. fused GEMM + bias + tanh over Mc compacted rows (early-exit beyond live tiles)
    {
        const int nwg = ((N + BM - 1) / BM) * (C / BN);
        gemm_tanh_kernel<<<nwg, 256, 0, stream>>>(Z, Wt_h, bias, mc, nodeid, out, K, C);
    }
}

// Round 4
// 543.391 us; speedup vs baseline: 1.0334x; 1.0334x over previous
//
#include <hip/hip_runtime.h>

typedef _Float16 half_t;
typedef __attribute__((ext_vector_type(8))) _Float16 half8;
typedef __attribute__((ext_vector_type(4))) float floatx4;

#define BM 256
#define BN 256
#define BK 64

// ---------------- conversion + rearrange: W[d][s*C+c] -> Wt[c][s*D+d] fp16 ----------------
// also computes tanh(bias) table (threads idx < C)
__global__ void cvt_w_kernel(const float* __restrict__ W, half_t* __restrict__ Wt,
                             const float* __restrict__ bias, float* __restrict__ tb,
                             int D, int C, int total) {
    int idx = blockIdx.x * blockDim.x + threadIdx.x;  // idx = c*1536 + s*512 + d
    if (idx >= total) return;
    if (idx < C) {
        float ex = __expf(2.0f * bias[idx]);
        tb[idx] = 1.0f - 2.0f / (ex + 1.0f);
    }
    int c = idx / 1536;
    int r = idx - c * 1536;           // s*512 + d
    int s = r >> 9;
    int d = r & 511;
    Wt[idx] = (half_t)W[(long)d * 1536 + s * 512 + c];
}

// ---------------- counting sort of edges by dst ----------------
__global__ void hist_kernel(const int* __restrict__ dst, int* __restrict__ deg, int E) {
    int e = blockIdx.x * blockDim.x + threadIdx.x;
    if (e < E) atomicAdd(&deg[dst[e]], 1);
}

// partial sums of deg AND of flag(deg>0), per 1024-element block
__global__ void scan_partial2_kernel(const int* __restrict__ deg,
                                     int* __restrict__ bsum, int* __restrict__ bsum2, int n) {
    __shared__ int wsum[4], wsum2[4];
    int t = threadIdx.x, lane = t & 63, w = t >> 6;
    int base = blockIdx.x * 1024 + t * 4;
    int s = 0, s2 = 0;
#pragma unroll
    for (int j = 0; j < 4; ++j) {
        int i = base + j;
        if (i < n) { int d = deg[i]; s += d; s2 += (d > 0); }
    }
#pragma unroll
    for (int o = 1; o < 64; o <<= 1) { s += __shfl_xor(s, o); s2 += __shfl_xor(s2, o); }
    if (lane == 0) { wsum[w] = s; wsum2[w] = s2; }
    __syncthreads();
    if (t == 0) {
        bsum[blockIdx.x]  = wsum[0]  + wsum[1]  + wsum[2]  + wsum[3];
        bsum2[blockIdx.x] = wsum2[0] + wsum2[1] + wsum2[2] + wsum2[3];
    }
}

// single-wave exclusive scan of up to 128 elements in-place; returns total
__device__ int exscan_wave128(int* arr, int nb, int lane) {
    int a0 = (lane < nb) ? arr[lane] : 0;
    int a1 = (64 + lane < nb) ? arr[64 + lane] : 0;
    int s0 = a0, s1 = a1;
#pragma unroll
    for (int o = 1; o < 64; o <<= 1) {
        int t0 = __shfl_up(s0, o); if (lane >= o) s0 += t0;
        int t1 = __shfl_up(s1, o); if (lane >= o) s1 += t1;
    }
    s1 += __shfl(s0, 63);
    int tot = __shfl(s1, 63);
    if (lane < nb) arr[lane] = s0 - a0;
    if (64 + lane < nb) arr[64 + lane] = s1 - a1;
    return tot;
}

__global__ void scan_bsums2_kernel(int* __restrict__ bsum, int* __restrict__ bsum2,
                                   int nb, int* __restrict__ mc) {
    int lane = threadIdx.x & 63;
    if (nb <= 128) {
        exscan_wave128(bsum, nb, lane);
        int tot = exscan_wave128(bsum2, nb, lane);
        if (lane == 0) *mc = tot;
    } else if (lane == 0) {
        int acc = 0, acc2 = 0;
        for (int i = 0; i < nb; ++i) {
            int v = bsum[i];  bsum[i] = acc;   acc += v;
            int v2 = bsum2[i]; bsum2[i] = acc2; acc2 += v2;
        }
        *mc = acc2;
    }
}

// final scan: edge offsets (off) + compact row rank + nodeid (compact->node)
__global__ void scan_final2_kernel(const int* __restrict__ deg,
                                   const int* __restrict__ bsum, const int* __restrict__ bsum2,
                                   int* __restrict__ off, int* __restrict__ rank,
                                   int* __restrict__ nodeid, int n) {
    __shared__ int wsum[4], wsum2[4];
    int t = threadIdx.x, lane = t & 63, w = t >> 6;
    int base = blockIdx.x * 1024 + t * 4;
    int v[4]; int s = 0, s2 = 0;
#pragma unroll
    for (int j = 0; j < 4; ++j) {
        int i = base + j;
        v[j] = (i < n) ? deg[i] : 0;
        s += v[j]; s2 += (v[j] > 0);
    }
    int sc = s, sc2 = s2;
#pragma unroll
    for (int o = 1; o < 64; o <<= 1) {
        int u  = __shfl_up(sc, o);  if (lane >= o) sc  += u;
        int u2 = __shfl_up(sc2, o); if (lane >= o) sc2 += u2;
    }
    if (lane == 63) { wsum[w] = sc; wsum2[w] = sc2; }
    __syncthreads();
    int woff = 0, woff2 = 0;
    for (int i = 0; i < w; ++i) { woff += wsum[i]; woff2 += wsum2[i]; }
    int ex  = bsum[blockIdx.x]  + woff  + (sc  - s);
    int ex2 = bsum2[blockIdx.x] + woff2 + (sc2 - s2);
#pragma unroll
    for (int j = 0; j < 4; ++j) {
        int i = base + j;
        if (i < n) {
            off[i] = ex;
            if (v[j] > 0) { rank[i] = ex2; nodeid[ex2] = i; ex2++; }
            ex += v[j];
        }
    }
}

// scatter: edges sorted by dst; also pre-gathers src + eta so aggx has a 2-level chain
__global__ void scatter_kernel(const int* __restrict__ dst, const int* __restrict__ src,
                               const float* __restrict__ eta,
                               const int* __restrict__ off, int* __restrict__ cursor,
                               int* __restrict__ srcs, floatx4* __restrict__ etas, int E) {
    int e = blockIdx.x * blockDim.x + threadIdx.x;
    if (e >= E) return;
    int d = dst[e];
    int p = off[d] + atomicAdd(&cursor[d], 1);
    srcs[p] = src[e];
    floatx4 et;
    et[0] = eta[3 * e + 0]; et[1] = eta[3 * e + 1]; et[2] = eta[3 * e + 2]; et[3] = 0.0f;
    etas[p] = et;
}

// ---------------- pre-aggregation: compacted Z[rank[n]][s*D+d]; deg-0 -> out=tanh(bias) ----------------
__global__ __launch_bounds__(256) void aggx_kernel(
    const float* __restrict__ x, const int* __restrict__ srcs,
    const floatx4* __restrict__ etas, const int* __restrict__ off,
    const int* __restrict__ deg, const int* __restrict__ rank,
    const float* __restrict__ tb, float* __restrict__ out,
    half_t* __restrict__ Z, int N, int D, int C)
{
    int node = blockIdx.x * 4 + (threadIdx.x >> 6);
    if (node >= N) return;
    int lane = threadIdx.x & 63;
    int d = deg[node];
    if (d == 0) {
        // no in-edges: out row = tanh(bias) (precomputed); nontemporal (write-once, never re-read)
        float* o = out + (long)node * C;
        for (int c0 = lane * 8; c0 < C; c0 += 64 * 8) {
            floatx4 v0 = *(const floatx4*)(tb + c0);
            floatx4 v1 = *(const floatx4*)(tb + c0 + 4);
            __builtin_nontemporal_store(v0, (floatx4*)(o + c0));
            __builtin_nontemporal_store(v1, (floatx4*)(o + c0 + 4));
        }
        return;
    }

    float a0[8] = {}, a1[8] = {}, a2[8] = {};
    int start = off[node];
    for (int q = 0; q < d; ++q) {
        int s = srcs[start + q];          // wave-uniform broadcast
        floatx4 et = etas[start + q];     // wave-uniform broadcast
        const float* xr = x + (long)s * D + lane * 8;
        floatx4 v0 = *(const floatx4*)xr;
        floatx4 v1 = *(const floatx4*)(xr + 4);
#pragma unroll
        for (int j = 0; j < 4; ++j) {
            a0[j] += et[0] * v0[j]; a0[j + 4] += et[0] * v1[j];
            a1[j] += et[1] * v0[j]; a1[j + 4] += et[1] * v1[j];
            a2[j] += et[2] * v0[j]; a2[j + 4] += et[2] * v1[j];
        }
    }
    half_t* zr = Z + (long)rank[node] * (3 * D) + lane * 8;
    half8 h0, h1, h2;
#pragma unroll
    for (int j = 0; j < 8; ++j) { h0[j] = (half_t)a0[j]; h1[j] = (half_t)a1[j]; h2[j] = (half_t)a2[j]; }
    *(half8*)zr = h0;
    *(half8*)(zr + D) = h1;
    *(half8*)(zr + 2 * D) = h2;
}

// ---------------- GEMM + bias + tanh over compacted rows, epilogue scatter ----------------
// 256^2 tile, BK=64, 8 waves (2M x 4N), double-buffered 128KB LDS (1 block/CU).
// SAME sync structure as the proven 128^2 version (STAGE next -> counted vmcnt ->
// barrier -> compute -> barrier), but 4x more MFMA per sync period: the per-tile
// compute window (~2500 cy) now covers load latency with 1-deep prefetch, and
// staged bytes per FLOP are halved. R3 post-mortem: depth-3 prefetch at 128^2
// regressed (occupancy 3->2 blocks); the convoy overhead per K-step was the real
// cost, so amortize it instead.
__global__ __launch_bounds__(512, 2) void gemm_tanh_kernel(
    const half_t* __restrict__ A,    // compacted Z: [Mc][K], K=1536 (rows >= Mc garbage, discarded)
    const half_t* __restrict__ Bt,   // Wt: [C][K]
    const float* __restrict__ bias,  // [C]
    const int* __restrict__ mc_ptr,  // &Mc
    const int* __restrict__ nodeid,  // compact row -> node
    float* __restrict__ out,         // [N][C]
    int K, int C)
{
    // [dbuf][half 128-rows][128*64]
    __shared__ half_t As[2][2][128 * 64];
    __shared__ half_t Bs[2][2][128 * 64];

    const int Mc = *mc_ptr;
    const int ncol = C / BN;                         // 2
    const int T = ((Mc + BM - 1) / BM) * ncol;       // live tiles
    const int b = blockIdx.x;
    if (b >= T) return;
    // bijective XCD swizzle (m204): contiguous tile chunk per XCD, cols fastest
    const int qq = T >> 3, rem = T & 7;
    const int xcd = b & 7, ib = b >> 3;
    const int wg = (xcd < rem ? xcd * (qq + 1) : rem * (qq + 1) + (xcd - rem) * qq) + ib;
    const int n0 = (wg % ncol) * BN;
    const int m0 = (wg / ncol) * BM;

    const int t    = threadIdx.x;      // 0..511
    const int lane = t & 63;
    const int wave = t >> 6;           // 0..7; 2M x 4N
    const int wm   = (wave >> 2) * 128;
    const int wn   = (wave & 3) * 64;
    const int hA   = wave >> 2;        // which A-half this wave reads
    const int hB   = (wave & 3) >> 1;  // which B-half
    const int cb   = (wave & 1) * 64;  // col base within B-half

    // ---- staging geometry (per thread: 8 x global_load_lds(16B) per K-tile) ----
    // half-tile = 128 rows x 64 k (16KB); slot = q*512 + t; row_local = q*64 + (t>>3);
    // LDS slot (row, oct) holds global k-octet oct ^ (row&7)  [bank swizzle, rule #21:
    // source pre-swizzled, dest linear, read applies same XOR].
    const int r1 = t >> 3;                                 // 0..63
    const int k8 = (((t & 7) ^ ((t >> 3) & 7))) * 8;       // swizzled source k-octet
    // A rows: m0 + {0,64,128,192} + r1 ; B rows: n0 + same
    const long gA0 = (long)(m0 + r1)       * K + k8;
    const long gA1 = (long)(m0 + 64 + r1)  * K + k8;
    const long gA2 = (long)(m0 + 128 + r1) * K + k8;
    const long gA3 = (long)(m0 + 192 + r1) * K + k8;
    const long gB0 = (long)(n0 + r1)       * K + k8;
    const long gB1 = (long)(n0 + 64 + r1)  * K + k8;
    const long gB2 = (long)(n0 + 128 + r1) * K + k8;
    const long gB3 = (long)(n0 + 192 + r1) * K + k8;

    floatx4 acc[8][4] = {};

    // ---- fragment-read geometry ----
    // A lane layout: row = lane&15 (+i*16), k = kk*32 + (lane>>4)*8. row&7 = lane&7.
    const int aBase = (lane & 15) * 64;              // row' * 64 (halfs)
    const int bBase = (cb + (lane & 15)) * 64;
    const int c0 = (((lane >> 4)) ^ (lane & 7)) * 8;       // kk=0 swizzled octet
    const int c1 = (((lane >> 4) + 4) ^ (lane & 7)) * 8;   // kk=1

#define STAGE(buf, ktk)                                                                     \
    do {                                                                                    \
        __builtin_amdgcn_global_load_lds(                                                   \
            (const __attribute__((address_space(1))) void*)(A + gA0 + (ktk)),               \
            (__attribute__((address_space(3))) void*)(&As[buf][0][t * 8]), 16, 0, 0);       \
        __builtin_amdgcn_global_load_lds(                                                   \
            (const __attribute__((address_space(1))) void*)(A + gA1 + (ktk)),               \
            (__attribute__((address_space(3))) void*)(&As[buf][0][(512 + t) * 8]), 16, 0, 0); \
        __builtin_amdgcn_global_load_lds(                                                   \
            (const __attribute__((address_space(1))) void*)(A + gA2 + (ktk)),               \
            (__attribute__((address_space(3))) void*)(&As[buf][1][t * 8]), 16, 0, 0);       \
        __builtin_amdgcn_global_load_lds(                                                   \
            (const __attribute__((address_space(1))) void*)(A + gA3 + (ktk)),               \
            (__attribute__((address_space(3))) void*)(&As[buf][1][(512 + t) * 8]), 16, 0, 0); \
        __builtin_amdgcn_global_load_lds(                                                   \
            (const __attribute__((address_space(1))) void*)(Bt + gB0 + (ktk)),              \
            (__attribute__((address_space(3))) void*)(&Bs[buf][0][t * 8]), 16, 0, 0);       \
        __builtin_amdgcn_global_load_lds(                                                   \
            (const __attribute__((address_space(1))) void*)(Bt + gB1 + (ktk)),              \
            (__attribute__((address_space(3))) void*)(&Bs[buf][0][(512 + t) * 8]), 16, 0, 0); \
        __builtin_amdgcn_global_load_lds(                                                   \
            (const __attribute__((address_space(1))) void*)(Bt + gB2 + (ktk)),              \
            (__attribute__((address_space(3))) void*)(&Bs[buf][1][t * 8]), 16, 0, 0);       \
        __builtin_amdgcn_global_load_lds(                                                   \
            (const __attribute__((address_space(1))) void*)(Bt + gB3 + (ktk)),              \
            (__attribute__((address_space(3))) void*)(&Bs[buf][1][(512 + t) * 8]), 16, 0, 0); \
    } while (0)

#define COMPUTE(buf)                                                                        \
    do {                                                                                    \
        const half_t* Ab = &As[buf][hA][0];                                                 \
        const half_t* Bb = &Bs[buf][hB][0];                                                 \
        half8 a[8], bf[4];                                                                  \
        _Pragma("unroll") for (int i = 0; i < 8; ++i)                                       \
            a[i] = *(const half8*)&Ab[aBase + i * 1024 + c0];                               \
        _Pragma("unroll") for (int j = 0; j < 4; ++j)                                       \
            bf[j] = *(const half8*)&Bb[bBase + j * 1024 + c0];                              \
        _Pragma("unroll") for (int i = 0; i < 8; ++i)                                       \
            _Pragma("unroll") for (int j = 0; j < 4; ++j)                                   \
                acc[i][j] = __builtin_amdgcn_mfma_f32_16x16x32_f16(a[i], bf[j],             \
                                                                   acc[i][j], 0, 0, 0);    \
        _Pragma("unroll") for (int i = 0; i < 8; ++i)                                       \
            a[i] = *(const half8*)&Ab[aBase + i * 1024 + c1];                               \
        _Pragma("unroll") for (int j = 0; j < 4; ++j)                                       \
            bf[j] = *(const half8*)&Bb[bBase + j * 1024 + c1];                              \
        _Pragma("unroll") for (int i = 0; i < 8; ++i)                                       \
            _Pragma("unroll") for (int j = 0; j < 4; ++j)                                   \
                acc[i][j] = __builtin_amdgcn_mfma_f32_16x16x32_f16(a[i], bf[j],             \
                                                                   acc[i][j], 0, 0, 0);    \
    } while (0)

    const int nt = K / BK;   // 24
    STAGE(0, 0);
    for (int kt = 0; kt < nt; ++kt) {
        if (kt + 1 < nt) {
            STAGE((kt + 1) & 1, (kt + 1) * BK);            // 16 loads in flight
            asm volatile("s_waitcnt vmcnt(8)" ::: "memory"); // retire tile kt's 8
        } else {
            asm volatile("s_waitcnt vmcnt(0)" ::: "memory");
        }
        __builtin_amdgcn_sched_barrier(0);
        __builtin_amdgcn_s_barrier();                      // buf[kt&1] complete
        __builtin_amdgcn_sched_barrier(0);
        COMPUTE(kt & 1);
        __builtin_amdgcn_sched_barrier(0);
        __builtin_amdgcn_s_barrier();                      // all done reading buf[kt&1]
        __builtin_amdgcn_sched_barrier(0);
    }

#undef STAGE
#undef COMPUTE

    // epilogue: D[m][n]: col = lane&15, row = (lane>>4)*4 + reg; scatter via nodeid; bias+tanh
    // out is write-once, never re-read -> nontemporal (keep x/Z in L3)
    const int col0 = lane & 15;
    const int rbase = (lane >> 4) * 4;
    float bj[4];
#pragma unroll
    for (int j = 0; j < 4; ++j)
        bj[j] = bias[n0 + wn + col0 + j * 16];
#pragma unroll
    for (int i = 0; i < 8; ++i) {
#pragma unroll
        for (int rr = 0; rr < 4; ++rr) {
            int crow = m0 + wm + i * 16 + rbase + rr;
            if (crow >= Mc) continue;
            long base = (long)nodeid[crow] * C + n0 + wn + col0;
#pragma unroll
            for (int j = 0; j < 4; ++j) {
                float xv = acc[i][j][rr] + bj[j];
                float ex = __expf(2.0f * xv);
                __builtin_nontemporal_store(1.0f - 2.0f / (ex + 1.0f), &out[base + j * 16]);
            }
        }
    }
}

extern "C" void kernel_launch(void* const* d_in, const int* in_sizes, int n_in,
                              void* d_out, int out_size, void* d_ws, size_t ws_size,
                              hipStream_t stream) {
    const float* x    = (const float*)d_in[0];
    const float* W    = (const float*)d_in[1];
    const float* bias = (const float*)d_in[2];
    const float* eta  = (const float*)d_in[3];
    const int*   src  = (const int*)d_in[4];
    const int*   dst  = (const int*)d_in[5];
    float* out = (float*)d_out;

    const int  C   = in_sizes[2];          // 512
    const int  C3  = 3 * C;                // 1536
    const int  D   = in_sizes[1] / C3;     // 512
    const long xcount = in_sizes[0];       // N*D
    const int  N   = (int)(xcount / D);    // 100000
    const int  E   = in_sizes[4];          // 100000
    const int  K   = 3 * D;                // 1536 (GEMM inner dim)
    const int  Npad = ((N + BM - 1) / BM) * BM;   // Z padded so GEMM A-tiles never go OOB
    const int  nb  = (N + 1023) / 1024;
    const size_t nbPad = (size_t)((nb + 3) & ~3);

    auto alignup = [](size_t v) { return (v + 15) & ~(size_t)15; };

    // workspace: Z | Wt | deg | cursor | off | rank | nodeid | srcs | etas | bsum | bsum2 | mc | tb
    char* ws = (char*)d_ws;
    size_t o = 0;
    half_t* Z    = (half_t*)(ws + o); o += (size_t)Npad * K * sizeof(half_t);
    half_t* Wt_h = (half_t*)(ws + o); o += (size_t)C * K * sizeof(half_t);
    int* deg     = (int*)(ws + o);    o += (size_t)N * sizeof(int);
    int* cursor  = (int*)(ws + o);    o += (size_t)N * sizeof(int);
    int* off     = (int*)(ws + o);    o += (size_t)N * sizeof(int);
    int* rank    = (int*)(ws + o);    o += (size_t)N * sizeof(int);
    int* nodeid  = (int*)(ws + o);    o += (size_t)N * sizeof(int);
    int* srcs    = (int*)(ws + o);    o += (size_t)E * sizeof(int);
    o = alignup(o);
    floatx4* etas = (floatx4*)(ws + o); o += (size_t)E * sizeof(floatx4);
    int* bsum    = (int*)(ws + o);    o += nbPad * sizeof(int);
    int* bsum2   = (int*)(ws + o);    o += nbPad * sizeof(int);
    int* mc      = (int*)(ws + o);    o += 4 * sizeof(int);
    float* tb    = (float*)(ws + o);  o += (size_t)C * sizeof(float);

    // 0. zero deg + cursor (adjacent)
    hipMemsetAsync(deg, 0, 2 * (size_t)N * sizeof(int), stream);
    // 1. W -> fp16 [C][3*D] + tanh(bias) table
    cvt_w_kernel<<<(C * K + 255) / 256, 256, 0, stream>>>(W, Wt_h, bias, tb, D, C, C * K);
    // 2. counting sort of edges by dst + compaction scan (rank/nodeid/Mc)
    hist_kernel<<<(E + 255) / 256, 256, 0, stream>>>(dst, deg, E);
    scan_partial2_kernel<<<nb, 256, 0, stream>>>(deg, bsum, bsum2, N);
    scan_bsums2_kernel<<<1, 64, 0, stream>>>(bsum, bsum2, nb, mc);
    scan_final2_kernel<<<nb, 256, 0, stream>>>(deg, bsum, bsum2, off, rank, nodeid, N);
    scatter_kernel<<<(E + 255) / 256, 256, 0, stream>>>(dst, src, eta, off, cursor, srcs, etas, E);
    // 3. pre-aggregation -> compacted Z (fp16); deg-0 rows -> tanh(bias) row
    aggx_kernel<<<(N + 3) / 4, 256, 0, stream>>>(x, srcs, etas, off, deg, rank, tb, out, Z, N, D, C);
    // 4. fused GEMM + bias + tanh over Mc compacted rows (early-exit beyond live tiles)
    {
        const int nwg = (Npad / BM) * (C / BN);
        gemm_tanh_kernel<<<nwg, 512, 0, stream>>>(Z, Wt_h, bias, mc, nodeid, out, K, C);
    }
}